// Round 2
// baseline (8499.290 us; speedup 1.0000x reference)
//
#include <hip/hip_runtime.h>
#include <hip/hip_bf16.h>
#include <cstdint>
#include <cstddef>

// Problem constants
#define Bn 64
#define Pn 196
#define ENCn 2048
#define DECn 512
#define ATTn 512
#define En 300
#define Vn 30000
#define Tn 21
#define STEPSn 20
#define Gn 2048        // 4*DEC gate width
#define KALLn 2860     // En + ENCn + DECn

// ---- workspace layout (float offsets) ----
#define WS_ENCPROJ ((size_t)0)                            // [64*196][512]
#define WS_WT    (WS_ENCPROJ + (size_t)Bn*Pn*ATTn)        // [2348][2048] = W_ih^T
#define WS_CTX   (WS_WT + (size_t)(En+ENCn)*Gn)           // [64][2048] (also mean_f pre-loop)
#define WS_H0    (WS_CTX + (size_t)Bn*ENCn)               // [64][512]
#define WS_C     (WS_H0 + (size_t)Bn*DECn)                // [64][512]
#define WS_HDEC  (WS_C + (size_t)Bn*DECn)                 // [64][512]
#define WS_HALL  (WS_HDEC + (size_t)Bn*DECn)              // [64][20][512] row r=b*20+t
// total = 12,115,968 floats = 46.2 MiB

// ---- output layout (float offsets into d_out) ----
#define OUT_ALPHAS ((size_t)Bn*STEPSn*Vn)                 // 38,400,000
#define OUT_CAPT   (OUT_ALPHAS + (size_t)Bn*STEPSn*Pn)
#define OUT_SEQ    (OUT_CAPT + (size_t)Bn*Tn)

// ============ generic 128x128 tiled GEMM: C[r][c] = A[r][:K] @ B[:K][c] + bias[c]
// grid (M/128, ceil(N/128)), 256 threads, 8x8 per thread, BK=16.
// Requires: M%128==0, K%16==0, N%8==0.
__global__ __launch_bounds__(256) void k_gemm128(const float* __restrict__ A,
                                                 const float* __restrict__ B,
                                                 const float* __restrict__ bias,
                                                 float* __restrict__ C,
                                                 int N, int K) {
    __shared__ float As[16][128];   // [k][m]
    __shared__ float Bs[16][128];   // [k][n]
    int r0 = blockIdx.x * 128, c0 = blockIdx.y * 128;
    int tid = threadIdx.x;
    int tx = tid & 15, ty = tid >> 4;
    // A-load mapping: row lr, k-offset lk (8 wide)
    int lr = tid >> 1, lk = (tid & 1) * 8;
    // B-load mapping: k-row lkb, col lc (8 wide)
    int lkb = tid >> 4, lc = (tid & 15) * 8;
    int bc = c0 + lc;
    bool bok = (bc < N);

    float acc[8][8];
    #pragma unroll
    for (int i = 0; i < 8; ++i)
        #pragma unroll
        for (int j = 0; j < 8; ++j) acc[i][j] = 0.f;

    for (int k0 = 0; k0 < K; k0 += 16) {
        {
            const float* Ap = A + (size_t)(r0 + lr) * K + k0 + lk;
            float4 a0 = *(const float4*)Ap;
            float4 a1 = *(const float4*)(Ap + 4);
            As[lk + 0][lr] = a0.x; As[lk + 1][lr] = a0.y;
            As[lk + 2][lr] = a0.z; As[lk + 3][lr] = a0.w;
            As[lk + 4][lr] = a1.x; As[lk + 5][lr] = a1.y;
            As[lk + 6][lr] = a1.z; As[lk + 7][lr] = a1.w;
        }
        {
            float4 b0 = make_float4(0.f, 0.f, 0.f, 0.f), b1 = b0;
            if (bok) {
                const float* Bp = B + (size_t)(k0 + lkb) * N + bc;
                b0 = *(const float4*)Bp;
                b1 = *(const float4*)(Bp + 4);
            }
            *(float4*)&Bs[lkb][lc] = b0;
            *(float4*)&Bs[lkb][lc + 4] = b1;
        }
        __syncthreads();
        #pragma unroll
        for (int kk = 0; kk < 16; ++kk) {
            float4 aA = *(const float4*)&As[kk][ty * 8];
            float4 aB = *(const float4*)&As[kk][ty * 8 + 4];
            float4 bA = *(const float4*)&Bs[kk][tx * 8];
            float4 bB = *(const float4*)&Bs[kk][tx * 8 + 4];
            float a[8] = {aA.x, aA.y, aA.z, aA.w, aB.x, aB.y, aB.z, aB.w};
            float bb[8] = {bA.x, bA.y, bA.z, bA.w, bB.x, bB.y, bB.z, bB.w};
            #pragma unroll
            for (int i = 0; i < 8; ++i)
                #pragma unroll
                for (int j = 0; j < 8; ++j) acc[i][j] += a[i] * bb[j];
        }
        __syncthreads();
    }
    #pragma unroll
    for (int i = 0; i < 8; ++i) {
        int r = r0 + ty * 8 + i;
        #pragma unroll
        for (int j = 0; j < 8; ++j) {
            int c = c0 + tx * 8 + j;
            if (c < N) C[(size_t)r * N + c] = acc[i][j] + bias[c];
        }
    }
}

// ================= small precompute kernels =================

// mean over P: grid (64, 8)
__global__ __launch_bounds__(256) void k_mean(const float* __restrict__ feat,
                                              float* __restrict__ mean_f) {
    int b = blockIdx.x;
    int e = blockIdx.y * 256 + threadIdx.x;
    const float* fb = feat + (size_t)b * Pn * ENCn + e;
    float s = 0.f;
    #pragma unroll 4
    for (int p = 0; p < Pn; ++p) s += fb[(size_t)p * ENCn];
    mean_f[(size_t)b * ENCn + e] = s * (1.0f / (float)Pn);
}

// h0/c0 = mean_f @ W_h0/W_c0 + b ; grid (2, 16)
__global__ __launch_bounds__(256) void k_init_state(
        const float* __restrict__ mf,
        const float* __restrict__ Wh, const float* __restrict__ bh,
        const float* __restrict__ Wc, const float* __restrict__ bc,
        float* __restrict__ h, float* __restrict__ c) {
    int n = blockIdx.x * 256 + threadIdx.x;
    int b0 = blockIdx.y * 4;
    float ah[4], ac[4];
    float bhv = bh[n], bcv = bc[n];
    #pragma unroll
    for (int j = 0; j < 4; ++j) { ah[j] = bhv; ac[j] = bcv; }
    for (int k = 0; k < ENCn; ++k) {
        float wh = Wh[(size_t)k * DECn + n];
        float wc = Wc[(size_t)k * DECn + n];
        #pragma unroll
        for (int j = 0; j < 4; ++j) {
            float a = mf[(size_t)(b0 + j) * ENCn + k];
            ah[j] += a * wh;
            ac[j] += a * wc;
        }
    }
    #pragma unroll
    for (int j = 0; j < 4; ++j) {
        h[(size_t)(b0 + j) * DECn + n] = ah[j];
        c[(size_t)(b0 + j) * DECn + n] = ac[j];
    }
}

// transpose in[R][C] -> out[C][R]
__global__ __launch_bounds__(256) void k_transpose(const float* __restrict__ in,
                                                   float* __restrict__ out,
                                                   int R, int C) {
    __shared__ float tile[32][33];
    int c0 = blockIdx.x * 32, r0 = blockIdx.y * 32;
    int tx = threadIdx.x & 31, ty = threadIdx.x >> 5;
    for (int i = ty; i < 32; i += 8) {
        int r = r0 + i, cc = c0 + tx;
        tile[i][tx] = (r < R && cc < C) ? in[(size_t)r * C + cc] : 0.f;
    }
    __syncthreads();
    for (int i = ty; i < 32; i += 8) {
        int cc = c0 + i, r = r0 + tx;
        if (cc < C && r < R) out[(size_t)cc * R + r] = tile[tx][i];
    }
}

// captions + seq_length passthrough
__global__ __launch_bounds__(256) void k_tail(const int* __restrict__ captions,
                                              const int* __restrict__ caption_len,
                                              float* __restrict__ out) {
    int i = blockIdx.x * 256 + threadIdx.x;
    if (i < Bn * Tn) {
        out[OUT_CAPT + i] = (float)captions[i];
    } else if (i < Bn * Tn + Bn) {
        int b = i - Bn * Tn;
        out[OUT_SEQ + b] = (float)(caption_len[b] - 1);
    }
}

// ================= per-step kernels =================

// hdec = h_t @ W_dec + b_dec ; grid (8, 16)
__global__ __launch_bounds__(256) void k_hdec(const float* __restrict__ hbase, int hstride,
                                              const float* __restrict__ W_dec,
                                              const float* __restrict__ b_dec,
                                              float* __restrict__ hdec) {
    int c = blockIdx.x * 64 + (threadIdx.x & 63);
    int b = blockIdx.y * 4 + (threadIdx.x >> 6);
    const float* hp = hbase + (size_t)b * hstride;
    float acc = b_dec[c];
    #pragma unroll 4
    for (int k = 0; k < DECn; ++k) acc += hp[k] * W_dec[(size_t)k * DECn + c];
    hdec[(size_t)b * DECn + c] = acc;
}

// attention scores+softmax (redundant per y) + ctx slice ; grid (64, 4)
__global__ __launch_bounds__(256) void k_attnctx(const float* __restrict__ enc_proj,
                                                 const float* __restrict__ feat,
                                                 const float* __restrict__ hdec,
                                                 const float* __restrict__ W_att,
                                                 const float* __restrict__ b_att,
                                                 float* __restrict__ alphas_out,
                                                 float* __restrict__ ctx, int t) {
    __shared__ float hs[ATTn];
    __shared__ float wa[ATTn];
    __shared__ float al[Pn];
    __shared__ float red[4];
    int b = blockIdx.x, y = blockIdx.y, tid = threadIdx.x;
    for (int i = tid; i < ATTn; i += 256) {
        hs[i] = hdec[(size_t)b * ATTn + i];
        wa[i] = W_att[i];
    }
    __syncthreads();
    int wv = tid >> 6, lane = tid & 63;
    float batt = b_att[0];
    for (int p = wv; p < Pn; p += 4) {
        const float* ep = enc_proj + ((size_t)b * Pn + p) * ATTn;
        float s = 0.f;
        #pragma unroll 2
        for (int a = lane; a < ATTn; a += 64) {
            float v = ep[a] + hs[a];
            s += fmaxf(v, 0.f) * wa[a];
        }
        #pragma unroll
        for (int off = 32; off > 0; off >>= 1) s += __shfl_xor(s, off);
        if (lane == 0) al[p] = s + batt;
    }
    __syncthreads();
    float v = (tid < Pn) ? al[tid] : -1e30f;
    float m = v;
    #pragma unroll
    for (int off = 32; off > 0; off >>= 1) m = fmaxf(m, __shfl_xor(m, off));
    if (lane == 0) red[wv] = m;
    __syncthreads();
    float M = fmaxf(fmaxf(red[0], red[1]), fmaxf(red[2], red[3]));
    __syncthreads();
    float e = (tid < Pn) ? expf(v - M) : 0.f;
    float s = e;
    #pragma unroll
    for (int off = 32; off > 0; off >>= 1) s += __shfl_xor(s, off);
    if (lane == 0) red[wv] = s;
    __syncthreads();
    float S = red[0] + red[1] + red[2] + red[3];
    if (tid < Pn) {
        float an = e / S;
        al[tid] = an;
        if (y == 0) alphas_out[((size_t)b * STEPSn + t) * Pn + tid] = an;
    }
    __syncthreads();
    // ctx slice: e-range [y*512, y*512+512), 2 per thread
    int e0 = y * 512 + tid;
    const float* fb = feat + (size_t)b * Pn * ENCn;
    float acc0 = 0.f, acc1 = 0.f;
    #pragma unroll 4
    for (int p = 0; p < Pn; ++p) {
        float av = al[p];
        const float* fr = fb + (size_t)p * ENCn;
        acc0 += av * fr[e0];
        acc1 += av * fr[e0 + 256];
    }
    ctx[(size_t)b * ENCn + e0] = acc0;
    ctx[(size_t)b * ENCn + e0 + 256] = acc1;
}

// gates + fused LSTM pointwise ; grid (32, 16): x->d-tile 16, y->b-tile 4
// thread: lane = gate(4) x d(16), wave = one batch
__global__ __launch_bounds__(256) void k_gateslstm(
        const float* __restrict__ WT,      // [2348][2048] = W_ih^T
        const float* __restrict__ Whh,     // [2048][512]  = W_hh (untransposed)
        const float* __restrict__ emb,
        const int* __restrict__ captions,
        const float* __restrict__ ctx,
        const float* __restrict__ hbase, int hstride,
        const float* __restrict__ b_ih, const float* __restrict__ b_hh,
        float* __restrict__ c,
        float* __restrict__ hall, int t) {
    __shared__ float sg[4][4][16];   // [gate][b-idx][d]
    int tid = threadIdx.x;
    int lane = tid & 63, wv = tid >> 6;
    int d0 = blockIdx.x * 16, b0 = blockIdx.y * 4;
    int gate = lane >> 4, dd = lane & 15;
    int d = d0 + dd;
    int grow = (gate << 9) + d;
    int b = b0 + wv;

    const float* er = emb + (size_t)captions[b * Tn + t] * En;
    const float* cx = ctx + (size_t)b * ENCn;
    const float* hp = hbase + (size_t)b * hstride;

    float acc = b_ih[grow] + b_hh[grow];
    const float* wih = WT + grow;
    #pragma unroll 4
    for (int k = 0; k < En; ++k) acc += er[k] * wih[(size_t)k * Gn];
    const float* wcx = WT + (size_t)En * Gn + grow;
    #pragma unroll 4
    for (int k = 0; k < ENCn; ++k) acc += cx[k] * wcx[(size_t)k * Gn];
    const float* wh = Whh + (size_t)grow * DECn;
    #pragma unroll 2
    for (int k = 0; k < DECn; k += 4) {
        float4 w4 = *(const float4*)&wh[k];
        float4 h4 = *(const float4*)&hp[k];
        acc += w4.x * h4.x + w4.y * h4.y + w4.z * h4.z + w4.w * h4.w;
    }
    sg[gate][wv][dd] = acc;
    __syncthreads();
    if (tid < 64) {
        int bi = tid >> 4, d2 = tid & 15;
        float gi = sg[0][bi][d2], gf = sg[1][bi][d2];
        float gg = sg[2][bi][d2], go = sg[3][bi][d2];
        int bb = b0 + bi, didx = d0 + d2;
        float si = 1.f / (1.f + expf(-gi));
        float sf = 1.f / (1.f + expf(-gf));
        float so = 1.f / (1.f + expf(-go));
        size_t cidx = (size_t)bb * DECn + didx;
        float cc = sf * c[cidx] + si * tanhf(gg);
        float hh = so * tanhf(cc);
        c[cidx] = cc;
        hall[((size_t)bb * STEPSn + t) * DECn + didx] = hh;
    }
}

// ================= launcher =================

extern "C" void kernel_launch(void* const* d_in, const int* in_sizes, int n_in,
                              void* d_out, int out_size, void* d_ws, size_t ws_size,
                              hipStream_t stream) {
    const float* features    = (const float*)d_in[0];
    const int*   captions    = (const int*)d_in[1];
    const int*   caption_len = (const int*)d_in[2];
    const float* emb         = (const float*)d_in[3];
    const float* W_enc       = (const float*)d_in[4];
    const float* b_enc       = (const float*)d_in[5];
    const float* W_dec       = (const float*)d_in[6];
    const float* b_dec       = (const float*)d_in[7];
    const float* W_att       = (const float*)d_in[8];
    const float* b_att       = (const float*)d_in[9];
    const float* W_h0        = (const float*)d_in[10];
    const float* b_h0        = (const float*)d_in[11];
    const float* W_c0        = (const float*)d_in[12];
    const float* b_c0        = (const float*)d_in[13];
    const float* W_ih        = (const float*)d_in[14];
    const float* b_ih        = (const float*)d_in[15];
    const float* W_hh        = (const float*)d_in[16];
    const float* b_hh        = (const float*)d_in[17];
    const float* W_out       = (const float*)d_in[18];
    const float* b_out       = (const float*)d_in[19];

    float* out = (float*)d_out;
    float* ws  = (float*)d_ws;

    float* ws_encproj = ws + WS_ENCPROJ;
    float* ws_WT      = ws + WS_WT;
    float* ws_ctx     = ws + WS_CTX;   // doubles as mean_f pre-loop
    float* ws_h0      = ws + WS_H0;
    float* ws_c       = ws + WS_C;
    float* ws_hdec    = ws + WS_HDEC;
    float* ws_hall    = ws + WS_HALL;

    // ---- precompute ----
    k_gemm128<<<dim3(Pn * Bn / 128, ATTn / 128), 256, 0, stream>>>(
        features, W_enc, b_enc, ws_encproj, ATTn, ENCn);
    k_mean<<<dim3(Bn, ENCn / 256), 256, 0, stream>>>(features, ws_ctx);
    k_transpose<<<dim3((En + ENCn + 31) / 32, Gn / 32), 256, 0, stream>>>(
        W_ih, ws_WT, Gn, En + ENCn);
    k_init_state<<<dim3(2, 16), 256, 0, stream>>>(ws_ctx, W_h0, b_h0, W_c0, b_c0,
                                                  ws_h0, ws_c);
    k_tail<<<dim3((Bn * Tn + Bn + 255) / 256), 256, 0, stream>>>(captions, caption_len, out);

    // ---- recurrence ----
    for (int t = 0; t < STEPSn; ++t) {
        const float* hbase = (t == 0) ? ws_h0 : (ws_hall + (size_t)(t - 1) * DECn);
        int hstride = (t == 0) ? DECn : (STEPSn * DECn);
        k_hdec<<<dim3(8, 16), 256, 0, stream>>>(hbase, hstride, W_dec, b_dec, ws_hdec);
        k_attnctx<<<dim3(Bn, 4), 256, 0, stream>>>(ws_encproj, features, ws_hdec,
                                                   W_att, b_att, out + OUT_ALPHAS,
                                                   ws_ctx, t);
        k_gateslstm<<<dim3(32, 16), 256, 0, stream>>>(ws_WT, W_hh, emb, captions,
                                                      ws_ctx, hbase, hstride,
                                                      b_ih, b_hh, ws_c, ws_hall, t);
    }

    // ---- batched logits: [1280,512] @ [512,30000] + b_out -> out rows r=b*20+t ----
    k_gemm128<<<dim3(Bn * STEPSn / 128, (Vn + 127) / 128), 256, 0, stream>>>(
        ws_hall, W_out, b_out, out, Vn, DECn);
}

// Round 3
// 6219.901 us; speedup vs baseline: 1.3665x; 1.3665x over previous
//
#include <hip/hip_runtime.h>
#include <hip/hip_bf16.h>
#include <cstdint>
#include <cstddef>

// Problem constants
#define Bn 64
#define Pn 196
#define ENCn 2048
#define DECn 512
#define ATTn 512
#define En 300
#define Vn 30000
#define Tn 21
#define STEPSn 20
#define Gn 2048        // 4*DEC gate width

// ---- workspace layout (float offsets) ----
#define WS_ENCPROJ ((size_t)0)                            // [64*196][512]; reused post-loop for Ah/Al
#define WS_WT    (WS_ENCPROJ + (size_t)Bn*Pn*ATTn)        // [2348][2048] = W_ih^T
#define WS_CTX   (WS_WT + (size_t)(En+ENCn)*Gn)           // [64][2048] (also mean_f pre-loop)
#define WS_H0    (WS_CTX + (size_t)Bn*ENCn)               // [64][512]
#define WS_C     (WS_H0 + (size_t)Bn*DECn)                // [64][512]
#define WS_HALL  (WS_C + (size_t)Bn*DECn)                 // [64][20][512] row r=b*20+t
// total ~46 MiB (same budget as round 2)

// ---- output layout (float offsets into d_out) ----
#define OUT_ALPHAS ((size_t)Bn*STEPSn*Vn)                 // 38,400,000
#define OUT_CAPT   (OUT_ALPHAS + (size_t)Bn*STEPSn*Pn)
#define OUT_SEQ    (OUT_CAPT + (size_t)Bn*Tn)

typedef __attribute__((ext_vector_type(8))) short short8;
typedef __attribute__((ext_vector_type(4))) short short4v;
typedef __attribute__((ext_vector_type(4))) float f32x4;

static __device__ __forceinline__ unsigned short f2bf(float f) {
    unsigned u = __float_as_uint(f);
    return (unsigned short)((u + 0x7FFFu + ((u >> 16) & 1u)) >> 16);
}

// ============ fp32 128x128 tiled GEMM (kept for enc_proj) ============
__global__ __launch_bounds__(256) void k_gemm128(const float* __restrict__ A,
                                                 const float* __restrict__ B,
                                                 const float* __restrict__ bias,
                                                 float* __restrict__ C,
                                                 int N, int K) {
    __shared__ float As[16][128];
    __shared__ float Bs[16][128];
    int r0 = blockIdx.x * 128, c0 = blockIdx.y * 128;
    int tid = threadIdx.x;
    int tx = tid & 15, ty = tid >> 4;
    int lr = tid >> 1, lk = (tid & 1) * 8;
    int lkb = tid >> 4, lc = (tid & 15) * 8;
    int bc = c0 + lc;
    bool bok = (bc < N);

    float acc[8][8];
    #pragma unroll
    for (int i = 0; i < 8; ++i)
        #pragma unroll
        for (int j = 0; j < 8; ++j) acc[i][j] = 0.f;

    for (int k0 = 0; k0 < K; k0 += 16) {
        {
            const float* Ap = A + (size_t)(r0 + lr) * K + k0 + lk;
            float4 a0 = *(const float4*)Ap;
            float4 a1 = *(const float4*)(Ap + 4);
            As[lk + 0][lr] = a0.x; As[lk + 1][lr] = a0.y;
            As[lk + 2][lr] = a0.z; As[lk + 3][lr] = a0.w;
            As[lk + 4][lr] = a1.x; As[lk + 5][lr] = a1.y;
            As[lk + 6][lr] = a1.z; As[lk + 7][lr] = a1.w;
        }
        {
            float4 b0 = make_float4(0.f, 0.f, 0.f, 0.f), b1 = b0;
            if (bok) {
                const float* Bp = B + (size_t)(k0 + lkb) * N + bc;
                b0 = *(const float4*)Bp;
                b1 = *(const float4*)(Bp + 4);
            }
            *(float4*)&Bs[lkb][lc] = b0;
            *(float4*)&Bs[lkb][lc + 4] = b1;
        }
        __syncthreads();
        #pragma unroll
        for (int kk = 0; kk < 16; ++kk) {
            float4 aA = *(const float4*)&As[kk][ty * 8];
            float4 aB = *(const float4*)&As[kk][ty * 8 + 4];
            float4 bA = *(const float4*)&Bs[kk][tx * 8];
            float4 bB = *(const float4*)&Bs[kk][tx * 8 + 4];
            float a[8] = {aA.x, aA.y, aA.z, aA.w, aB.x, aB.y, aB.z, aB.w};
            float bb[8] = {bA.x, bA.y, bA.z, bA.w, bB.x, bB.y, bB.z, bB.w};
            #pragma unroll
            for (int i = 0; i < 8; ++i)
                #pragma unroll
                for (int j = 0; j < 8; ++j) acc[i][j] += a[i] * bb[j];
        }
        __syncthreads();
    }
    #pragma unroll
    for (int i = 0; i < 8; ++i) {
        int r = r0 + ty * 8 + i;
        #pragma unroll
        for (int j = 0; j < 8; ++j) {
            int c = c0 + tx * 8 + j;
            if (c < N) C[(size_t)r * N + c] = acc[i][j] + bias[c];
        }
    }
}

// ================= small precompute kernels =================

__global__ __launch_bounds__(256) void k_mean(const float* __restrict__ feat,
                                              float* __restrict__ mean_f) {
    int b = blockIdx.x;
    int e = blockIdx.y * 256 + threadIdx.x;
    const float* fb = feat + (size_t)b * Pn * ENCn + e;
    float s = 0.f;
    #pragma unroll 4
    for (int p = 0; p < Pn; ++p) s += fb[(size_t)p * ENCn];
    mean_f[(size_t)b * ENCn + e] = s * (1.0f / (float)Pn);
}

__global__ __launch_bounds__(256) void k_init_state(
        const float* __restrict__ mf,
        const float* __restrict__ Wh, const float* __restrict__ bh,
        const float* __restrict__ Wc, const float* __restrict__ bc,
        float* __restrict__ h, float* __restrict__ c) {
    int n = blockIdx.x * 256 + threadIdx.x;
    int b0 = blockIdx.y * 4;
    float ah[4], ac[4];
    float bhv = bh[n], bcv = bc[n];
    #pragma unroll
    for (int j = 0; j < 4; ++j) { ah[j] = bhv; ac[j] = bcv; }
    for (int k = 0; k < ENCn; ++k) {
        float wh = Wh[(size_t)k * DECn + n];
        float wc = Wc[(size_t)k * DECn + n];
        #pragma unroll
        for (int j = 0; j < 4; ++j) {
            float a = mf[(size_t)(b0 + j) * ENCn + k];
            ah[j] += a * wh;
            ac[j] += a * wc;
        }
    }
    #pragma unroll
    for (int j = 0; j < 4; ++j) {
        h[(size_t)(b0 + j) * DECn + n] = ah[j];
        c[(size_t)(b0 + j) * DECn + n] = ac[j];
    }
}

__global__ __launch_bounds__(256) void k_transpose(const float* __restrict__ in,
                                                   float* __restrict__ out,
                                                   int R, int C) {
    __shared__ float tile[32][33];
    int c0 = blockIdx.x * 32, r0 = blockIdx.y * 32;
    int tx = threadIdx.x & 31, ty = threadIdx.x >> 5;
    for (int i = ty; i < 32; i += 8) {
        int r = r0 + i, cc = c0 + tx;
        tile[i][tx] = (r < R && cc < C) ? in[(size_t)r * C + cc] : 0.f;
    }
    __syncthreads();
    for (int i = ty; i < 32; i += 8) {
        int cc = c0 + i, r = r0 + tx;
        if (cc < C && r < R) out[(size_t)cc * R + r] = tile[tx][i];
    }
}

__global__ __launch_bounds__(256) void k_tail(const int* __restrict__ captions,
                                              const int* __restrict__ caption_len,
                                              float* __restrict__ out) {
    int i = blockIdx.x * 256 + threadIdx.x;
    if (i < Bn * Tn) {
        out[OUT_CAPT + i] = (float)captions[i];
    } else if (i < Bn * Tn + Bn) {
        int b = i - Bn * Tn;
        out[OUT_SEQ + b] = (float)(caption_len[b] - 1);
    }
}

// ================= per-step kernel 1: hdec + attention + ctx =================
// grid 256 flat: b = bid&63, y = bid>>6  (XCD = bid%8 = b%8 -> per-b L2 locality)
__global__ __launch_bounds__(256) void k_step1(const float* __restrict__ enc_proj,
                                               const float* __restrict__ feat,
                                               const float* __restrict__ hbase, int hstride,
                                               const float* __restrict__ W_dec,
                                               const float* __restrict__ b_dec,
                                               const float* __restrict__ W_att,
                                               const float* __restrict__ b_att,
                                               float* __restrict__ alphas_out,
                                               float* __restrict__ ctx, int t) {
    __shared__ float hv[DECn];
    __shared__ float hs[ATTn];
    __shared__ float wa[ATTn];
    __shared__ float al[Pn];
    __shared__ float red[4];
    int bid = blockIdx.x;
    int b = bid & 63, y = bid >> 6;
    int tid = threadIdx.x;
    hv[tid]       = hbase[(size_t)b * hstride + tid];
    hv[tid + 256] = hbase[(size_t)b * hstride + tid + 256];
    wa[tid]       = W_att[tid];
    wa[tid + 256] = W_att[tid + 256];
    __syncthreads();
    // hdec = h @ W_dec + b_dec (redundant across 4 y-blocks; W_dec is L2-hot)
    {
        float acc0 = b_dec[tid], acc1 = b_dec[tid + 256];
        const float* wd = W_dec + tid;
        #pragma unroll 8
        for (int k = 0; k < DECn; ++k) {
            float h = hv[k];
            acc0 += h * wd[(size_t)k * DECn];
            acc1 += h * wd[(size_t)k * DECn + 256];
        }
        hs[tid] = acc0;
        hs[tid + 256] = acc1;
    }
    __syncthreads();
    int wv = tid >> 6, lane = tid & 63;
    float batt = b_att[0];
    for (int p = wv; p < Pn; p += 4) {
        const float* ep = enc_proj + ((size_t)b * Pn + p) * ATTn;
        float s = 0.f;
        #pragma unroll 2
        for (int a = lane; a < ATTn; a += 64) {
            float v = ep[a] + hs[a];
            s += fmaxf(v, 0.f) * wa[a];
        }
        #pragma unroll
        for (int off = 32; off > 0; off >>= 1) s += __shfl_xor(s, off);
        if (lane == 0) al[p] = s + batt;
    }
    __syncthreads();
    float v = (tid < Pn) ? al[tid] : -1e30f;
    float m = v;
    #pragma unroll
    for (int off = 32; off > 0; off >>= 1) m = fmaxf(m, __shfl_xor(m, off));
    if (lane == 0) red[wv] = m;
    __syncthreads();
    float M = fmaxf(fmaxf(red[0], red[1]), fmaxf(red[2], red[3]));
    __syncthreads();
    float e = (tid < Pn) ? expf(v - M) : 0.f;
    float s = e;
    #pragma unroll
    for (int off = 32; off > 0; off >>= 1) s += __shfl_xor(s, off);
    if (lane == 0) red[wv] = s;
    __syncthreads();
    float S = red[0] + red[1] + red[2] + red[3];
    if (tid < Pn) {
        float an = e / S;
        al[tid] = an;
        if (y == 0) alphas_out[((size_t)b * STEPSn + t) * Pn + tid] = an;
    }
    __syncthreads();
    // ctx slice: e-range [y*512, y*512+512)
    int e0 = y * 512 + tid;
    const float* fb = feat + (size_t)b * Pn * ENCn;
    float acc0 = 0.f, acc1 = 0.f;
    #pragma unroll 4
    for (int p = 0; p < Pn; ++p) {
        float av = al[p];
        const float* fr = fb + (size_t)p * ENCn;
        acc0 += av * fr[e0];
        acc1 += av * fr[e0 + 256];
    }
    ctx[(size_t)b * ENCn + e0] = acc0;
    ctx[(size_t)b * ENCn + e0 + 256] = acc1;
}

// ================= per-step kernel 2: gates + LSTM =================
// grid 256 flat: x = bid&31 (16-d slice), ybk = bid>>5 (8-b slice); XCD = x%8
// thread: lane -> (gate, d); wv -> 2 batches. A-panel in LDS, weights from L2.
__global__ __launch_bounds__(256) void k_step2(const float* __restrict__ WT,
                                               const float* __restrict__ emb,
                                               const int* __restrict__ captions,
                                               const float* __restrict__ ctx,
                                               const float* __restrict__ hbase, int hstride,
                                               const float* __restrict__ b_ih,
                                               const float* __restrict__ b_hh,
                                               float* __restrict__ c,
                                               float* __restrict__ hall, int t) {
    __shared__ float Ap[8][516];
    __shared__ float sg[4][16][8];
    int bid = blockIdx.x;
    int x = bid & 31, ybk = bid >> 5;
    int tid = threadIdx.x;
    int lane = tid & 63, wv = tid >> 6;
    int gate = lane >> 4, dd = lane & 15;
    int g = (gate << 9) + x * 16 + dd;
    int b0 = ybk * 8;

    float bias = b_ih[g] + b_hh[g];
    float acc0 = bias, acc1 = bias;
    // bias is per-output; acc0/acc1 are two different b with same g -> both start at bias,
    // but only one copy of bias belongs to each output. Correct: each output = bias + dot.

    const int cbase[6] = {0, 512, 1024, 1536, 2048, 2560};
    for (int ch = 0; ch < 6; ++ch) {
        int base = cbase[ch];
        int klen = (ch == 5) ? 300 : 512;
        __syncthreads();
        // stage A-panel [8 b][klen]
        int qpb = klen >> 2;
        for (int q = tid; q < (qpb << 3); q += 256) {
            int bb = q / qpb;
            int kq = q - bb * qpb;
            int kg = base + kq * 4;
            int bglob = b0 + bb;
            const float* src;
            if (kg < En) src = emb + (size_t)captions[bglob * Tn + t] * En + kg;
            else if (kg < En + ENCn) src = ctx + (size_t)bglob * ENCn + (kg - En);
            else src = hbase + (size_t)bglob * hstride + (kg - En - ENCn);
            *(float4*)&Ap[bb][kq * 4] = *(const float4*)src;
        }
        __syncthreads();
        const float* wp = WT + (size_t)base * Gn + g;
        const float* a0p = &Ap[wv * 2][0];
        const float* a1p = &Ap[wv * 2 + 1][0];
        #pragma unroll 2
        for (int k = 0; k < klen; k += 4) {
            float4 a0 = *(const float4*)(a0p + k);
            float4 a1 = *(const float4*)(a1p + k);
            float w0 = wp[(size_t)k * Gn];
            float w1 = wp[(size_t)(k + 1) * Gn];
            float w2 = wp[(size_t)(k + 2) * Gn];
            float w3 = wp[(size_t)(k + 3) * Gn];
            acc0 += w0 * a0.x + w1 * a0.y + w2 * a0.z + w3 * a0.w;
            acc1 += w0 * a1.x + w1 * a1.y + w2 * a1.z + w3 * a1.w;
        }
    }
    sg[gate][dd][wv * 2]     = acc0;
    sg[gate][dd][wv * 2 + 1] = acc1;
    __syncthreads();
    if (tid < 128) {
        int dl = tid & 15, bl = tid >> 4;
        float gi = sg[0][dl][bl], gf = sg[1][dl][bl];
        float gg = sg[2][dl][bl], go = sg[3][dl][bl];
        int bglob = b0 + bl, d = x * 16 + dl;
        float si = 1.f / (1.f + expf(-gi));
        float sf = 1.f / (1.f + expf(-gf));
        float so = 1.f / (1.f + expf(-go));
        size_t cidx = (size_t)bglob * DECn + d;
        float cc = sf * c[cidx] + si * tanhf(gg);
        float hh = so * tanhf(cc);
        c[cidx] = cc;
        hall[((size_t)bglob * STEPSn + t) * DECn + d] = hh;
    }
}

// ================= logits via split-bf16 MFMA =================

// hall fp32 [1280][512] -> Ah, Al bf16(short) [1280][512]
__global__ __launch_bounds__(256) void k_splitA(const float* __restrict__ hall,
                                                short* __restrict__ Ah,
                                                short* __restrict__ Al) {
    int idx = blockIdx.x * 256 + threadIdx.x;   // 0..163839
    size_t base = (size_t)idx * 4;
    float4 v = *(const float4*)(hall + base);
    float a[4] = {v.x, v.y, v.z, v.w};
    short4v h, l;
    #pragma unroll
    for (int j = 0; j < 4; ++j) {
        unsigned short hi = f2bf(a[j]);
        float lo = a[j] - __uint_as_float((unsigned)hi << 16);
        h[j] = (short)hi;
        l[j] = (short)f2bf(lo);
    }
    *(short4v*)(Ah + base) = h;
    *(short4v*)(Al + base) = l;
}

// C[1280][30000] = A[1280][512] @ W_out[512][30000] + b_out
// grid 625 blocks: 48 vocab cols each (625*48 = 30000 exact). 4 waves.
// W_out tile converted to split-bf16 in LDS (transposed, padded rows); A from
// pre-split global arrays. 3-pass MFMA (AhBh + AhBl + AlBh) ~ fp32 accuracy.
__global__ __launch_bounds__(256) void k_logits_mfma(const short* __restrict__ Ah,
                                                     const short* __restrict__ Al,
                                                     const float* __restrict__ W_out,
                                                     const float* __restrict__ b_out,
                                                     float* __restrict__ out) {
    __shared__ short Bh[48][520];
    __shared__ short Bl[48][520];
    int n0 = blockIdx.x * 48;
    int tid = threadIdx.x;
    // stage + convert: 512 k x 48 n
    for (int q = tid; q < 6144; q += 256) {
        int cq = q % 12, k = q / 12;
        const float* src = W_out + (size_t)k * Vn + n0 + cq * 4;
        float4 v = *(const float4*)src;
        float a[4] = {v.x, v.y, v.z, v.w};
        #pragma unroll
        for (int j = 0; j < 4; ++j) {
            unsigned short hi = f2bf(a[j]);
            float lo = a[j] - __uint_as_float((unsigned)hi << 16);
            Bh[cq * 4 + j][k] = (short)hi;
            Bl[cq * 4 + j][k] = (short)f2bf(lo);
        }
    }
    __syncthreads();
    int w = tid >> 6, l = tid & 63;
    int lr = l & 15, lk = (l >> 4) * 8;
    float bias[3];
    #pragma unroll
    for (int nt = 0; nt < 3; ++nt) bias[nt] = b_out[n0 + nt * 16 + lr];

    for (int chunk = 0; chunk < 20; ++chunk) {
        int m0 = chunk * 64 + w * 16;
        f32x4 acc[3];
        #pragma unroll
        for (int nt = 0; nt < 3; ++nt) acc[nt] = (f32x4){0.f, 0.f, 0.f, 0.f};
        #pragma unroll 2
        for (int ks = 0; ks < 16; ++ks) {
            int k0 = ks * 32;
            short8 ah = *(const short8*)(Ah + (size_t)(m0 + lr) * DECn + k0 + lk);
            short8 al = *(const short8*)(Al + (size_t)(m0 + lr) * DECn + k0 + lk);
            #pragma unroll
            for (int nt = 0; nt < 3; ++nt) {
                short8 bh = *(const short8*)&Bh[nt * 16 + lr][k0 + lk];
                short8 bl = *(const short8*)&Bl[nt * 16 + lr][k0 + lk];
                acc[nt] = __builtin_amdgcn_mfma_f32_16x16x32_bf16(ah, bh, acc[nt], 0, 0, 0);
                acc[nt] = __builtin_amdgcn_mfma_f32_16x16x32_bf16(ah, bl, acc[nt], 0, 0, 0);
                acc[nt] = __builtin_amdgcn_mfma_f32_16x16x32_bf16(al, bh, acc[nt], 0, 0, 0);
            }
        }
        #pragma unroll
        for (int nt = 0; nt < 3; ++nt) {
            int n = n0 + nt * 16 + lr;
            #pragma unroll
            for (int r = 0; r < 4; ++r) {
                int m = m0 + (l >> 4) * 4 + r;
                out[(size_t)m * Vn + n] = acc[nt][r] + bias[nt];
            }
        }
    }
}

// ================= launcher =================

extern "C" void kernel_launch(void* const* d_in, const int* in_sizes, int n_in,
                              void* d_out, int out_size, void* d_ws, size_t ws_size,
                              hipStream_t stream) {
    const float* features    = (const float*)d_in[0];
    const int*   captions    = (const int*)d_in[1];
    const int*   caption_len = (const int*)d_in[2];
    const float* emb         = (const float*)d_in[3];
    const float* W_enc       = (const float*)d_in[4];
    const float* b_enc       = (const float*)d_in[5];
    const float* W_dec       = (const float*)d_in[6];
    const float* b_dec       = (const float*)d_in[7];
    const float* W_att       = (const float*)d_in[8];
    const float* b_att       = (const float*)d_in[9];
    const float* W_h0        = (const float*)d_in[10];
    const float* b_h0        = (const float*)d_in[11];
    const float* W_c0        = (const float*)d_in[12];
    const float* b_c0        = (const float*)d_in[13];
    const float* W_ih        = (const float*)d_in[14];
    const float* b_ih        = (const float*)d_in[15];
    const float* W_hh        = (const float*)d_in[16];
    const float* b_hh        = (const float*)d_in[17];
    const float* W_out       = (const float*)d_in[18];
    const float* b_out       = (const float*)d_in[19];

    float* out = (float*)d_out;
    float* ws  = (float*)d_ws;

    float* ws_encproj = ws + WS_ENCPROJ;
    float* ws_WT      = ws + WS_WT;
    float* ws_ctx     = ws + WS_CTX;
    float* ws_h0      = ws + WS_H0;
    float* ws_c       = ws + WS_C;
    float* ws_hall    = ws + WS_HALL;
    short* ws_Ah      = (short*)(ws + WS_ENCPROJ);   // reuse enc_proj region post-loop
    short* ws_Al      = ws_Ah + (size_t)Bn * STEPSn * DECn;

    // ---- precompute ----
    k_gemm128<<<dim3(Pn * Bn / 128, ATTn / 128), 256, 0, stream>>>(
        features, W_enc, b_enc, ws_encproj, ATTn, ENCn);
    k_mean<<<dim3(Bn, ENCn / 256), 256, 0, stream>>>(features, ws_ctx);
    k_transpose<<<dim3((En + ENCn + 31) / 32, Gn / 32), 256, 0, stream>>>(
        W_ih, ws_WT, Gn, En + ENCn);
    k_init_state<<<dim3(2, 16), 256, 0, stream>>>(ws_ctx, W_h0, b_h0, W_c0, b_c0,
                                                  ws_h0, ws_c);
    k_tail<<<dim3((Bn * Tn + Bn + 255) / 256), 256, 0, stream>>>(captions, caption_len, out);

    // ---- recurrence: 2 kernels per step ----
    for (int t = 0; t < STEPSn; ++t) {
        const float* hbase = (t == 0) ? ws_h0 : (ws_hall + (size_t)(t - 1) * DECn);
        int hstride = (t == 0) ? DECn : (STEPSn * DECn);
        k_step1<<<dim3(256), 256, 0, stream>>>(ws_encproj, features, hbase, hstride,
                                               W_dec, b_dec, W_att, b_att,
                                               out + OUT_ALPHAS, ws_ctx, t);
        k_step2<<<dim3(256), 256, 0, stream>>>(ws_WT, emb, captions, ws_ctx,
                                               hbase, hstride, b_ih, b_hh,
                                               ws_c, ws_hall, t);
    }

    // ---- logits: split A, then MFMA GEMM ----
    k_splitA<<<dim3(Bn * STEPSn * DECn / 1024), 256, 0, stream>>>(ws_hall, ws_Ah, ws_Al);
    k_logits_mfma<<<dim3(Vn / 48), 256, 0, stream>>>(ws_Ah, ws_Al, W_out, b_out, out);
}